// Round 3
// baseline (1041.468 us; speedup 1.0000x reference)
//
#include <hip/hip_runtime.h>
#include <stdint.h>

// Problem constants (fixed by reference)
#define BATCH 4
#define LTOT  1408      // NVARS*NPATCH = 22*64
#define HEADS 8
#define HD    64
#define DIMD  512
#define NKEEP 704       // L - int(0.5*L)
#define RBLK  176       // LTOT/8
#define SCAP  32        // sparse-correction capacity per row (max actual = 28)

// S-buffer swizzled index: 8 floats per key m, one 16B pad every 4 keys.
// Keeps each [8] row contiguous & 16B-aligned (PV reads 2x float4 broadcast),
// spreads strided scans over more bank-groups (writes 8-way, scans 4-way).
#define SIDX(m) (((m) << 3) + (((m) >> 2) << 2))
#define SLEN (SIDX(LTOT - 1) + 8)   // 12668 floats = 50.7KB

typedef unsigned int uint;

__device__ __forceinline__ uint fkey(float f) {
  // order-preserving map float -> uint (ascending)
  uint u = __float_as_uint(f);
  return u ^ ((uint)((int)u >> 31) | 0x80000000u);
}

// ---------------------------------------------------------------------------
// GEMM: C[M,N] = A[M,512] * W[N,512]^T.  128x128 tile, BK=16, 256 thr, 8x8 micro.
// MODE 0: qkv — scatter epilogue into Q/K/V [B,H,L,64], q scaled by 1/8.
// MODE 1: proj — plain store + bias add.
// ---------------------------------------------------------------------------
template<int MODE>
__global__ __launch_bounds__(256)
void gemm_k(const float* __restrict__ A, const float* __restrict__ W,
            const float* __restrict__ pb, float* __restrict__ C0,
            float* __restrict__ C1, float* __restrict__ C2, int ntiles)
{
  __shared__ float Ast[16][132];   // k-major, pad 132 (16B-aligned rows, bank-shifted)
  __shared__ float Bst[16][132];
  const int t  = threadIdx.x;
  const int mt = blockIdx.x / ntiles, nt = blockIdx.x % ntiles;
  const int m0 = mt * 128, n0 = nt * 128;
  const int lr = t >> 2;            // 0..63
  const int lk = (t & 3) << 2;      // 0,4,8,12
  const int tr = t >> 4, tc = t & 15;

  float acc[8][8];
#pragma unroll
  for (int i = 0; i < 8; ++i)
#pragma unroll
    for (int j = 0; j < 8; ++j) acc[i][j] = 0.f;

  for (int k0 = 0; k0 < DIMD; k0 += 16) {
#pragma unroll
    for (int hh = 0; hh < 2; ++hh) {
      const int row = lr + hh * 64;
      const float4 av = *(const float4*)(A + (size_t)(m0 + row) * DIMD + k0 + lk);
      Ast[lk + 0][row] = av.x; Ast[lk + 1][row] = av.y;
      Ast[lk + 2][row] = av.z; Ast[lk + 3][row] = av.w;
      const float4 wv = *(const float4*)(W + (size_t)(n0 + row) * DIMD + k0 + lk);
      Bst[lk + 0][row] = wv.x; Bst[lk + 1][row] = wv.y;
      Bst[lk + 2][row] = wv.z; Bst[lk + 3][row] = wv.w;
    }
    __syncthreads();
#pragma unroll
    for (int k = 0; k < 16; ++k) {
      const float4 a0 = *(const float4*)&Ast[k][tr * 8];
      const float4 a1 = *(const float4*)&Ast[k][tr * 8 + 4];
      const float4 b0 = *(const float4*)&Bst[k][tc * 8];
      const float4 b1 = *(const float4*)&Bst[k][tc * 8 + 4];
      const float a[8] = {a0.x,a0.y,a0.z,a0.w,a1.x,a1.y,a1.z,a1.w};
      const float b[8] = {b0.x,b0.y,b0.z,b0.w,b1.x,b1.y,b1.z,b1.w};
#pragma unroll
      for (int i = 0; i < 8; ++i)
#pragma unroll
        for (int j = 0; j < 8; ++j)
          acc[i][j] = fmaf(a[i], b[j], acc[i][j]);
    }
    __syncthreads();
  }

  const int nb = n0 + tc * 8;
  if (MODE == 0) {
    // n in [0,1536): which = n>>9, h = (n>>6)&7, d = n&63 (constant across the 8-chunk)
    const int which = nb >> 9;
    const int h  = (nb >> 6) & 7;
    const int d0 = nb & 63;
    float* dst = (which == 0) ? C0 : (which == 1) ? C1 : C2;
    const float scl = (which == 0) ? 0.125f : 1.0f;   // fold q * HD^-0.5
#pragma unroll
    for (int i = 0; i < 8; ++i) {
      const int gm = m0 + tr * 8 + i;
      const int bb = gm / LTOT, ll = gm % LTOT;
      float* p = dst + ((size_t)(bb * HEADS + h) * LTOT + ll) * HD + d0;
      float4 v0 = make_float4(acc[i][0]*scl, acc[i][1]*scl, acc[i][2]*scl, acc[i][3]*scl);
      float4 v1 = make_float4(acc[i][4]*scl, acc[i][5]*scl, acc[i][6]*scl, acc[i][7]*scl);
      *(float4*)p = v0;
      *(float4*)(p + 4) = v1;
    }
  } else {
    const float4 q0 = *(const float4*)(pb + nb);
    const float4 q1 = *(const float4*)(pb + nb + 4);
#pragma unroll
    for (int i = 0; i < 8; ++i) {
      const int gm = m0 + tr * 8 + i;
      float* p = C0 + (size_t)gm * DIMD + nb;
      float4 v0 = make_float4(acc[i][0]+q0.x, acc[i][1]+q0.y, acc[i][2]+q0.z, acc[i][3]+q0.w);
      float4 v1 = make_float4(acc[i][4]+q1.x, acc[i][5]+q1.y, acc[i][6]+q1.z, acc[i][7]+q1.w);
      *(float4*)p = v0;
      *(float4*)(p + 4) = v1;
    }
  }
}

// ---------------------------------------------------------------------------
// Sparse-bias builder. bias[h,l,m] = w2[h] (row-const, ordering/softmax
// invariant -> skipped) + (w0-w2)*S[l,m] + (w1-w2)*T[l,m] - w2*eye[l,m].
// S has <=21 nonzeros/row, T <=6, eye 1 -> <=28 sparse entries/row.
// One wave per row l: lane-strided scan of masks, ballot compaction.
// Entry: sIdx = (m<<2)|type, sCoef = mask value (type 0:S, 1:T, 2:diag).
// ---------------------------------------------------------------------------
__global__ __launch_bounds__(256)
void sbias_k(const float* __restrict__ masks, int* __restrict__ sIdx,
             float* __restrict__ sCoef, int* __restrict__ sCnt)
{
  const int l    = blockIdx.x * 4 + (threadIdx.x >> 6);   // 352 blocks * 4 waves
  const int lane = threadIdx.x & 63;
  const unsigned long long ltmask = (1ull << lane) - 1ull;
  const float* Sm = masks + ((size_t)l * 3 + 0) * LTOT;
  const float* Tm = masks + ((size_t)l * 3 + 1) * LTOT;
  int base = 0;
  for (int i = lane; i < LTOT; i += 64) {
    const float sv = Sm[i];
    const float tv = Tm[i];
    const unsigned long long bS = __ballot(sv != 0.f);
    if (sv != 0.f) {
      const int pos = base + __popcll(bS & ltmask);
      if (pos < SCAP) { sIdx[l * SCAP + pos] = (i << 2) | 0; sCoef[l * SCAP + pos] = sv; }
    }
    base += __popcll(bS);
    const unsigned long long bT = __ballot(tv != 0.f);
    if (tv != 0.f) {
      const int pos = base + __popcll(bT & ltmask);
      if (pos < SCAP) { sIdx[l * SCAP + pos] = (i << 2) | 1; sCoef[l * SCAP + pos] = tv; }
    }
    base += __popcll(bT);
    const unsigned long long bD = __ballot(i == l);
    if (i == l) {
      const int pos = base + __popcll(bD & ltmask);
      if (pos < SCAP) { sIdx[l * SCAP + pos] = (i << 2) | 2; sCoef[l * SCAP + pos] = 1.f; }
    }
    base += __popcll(bD);
  }
  if (lane == 0) sCnt[l] = (base < SCAP) ? base : SCAP;
}

// ---------------------------------------------------------------------------
// Fused attention: per block = 8 query rows of one (b,h).
// Phases: scores (K-tiles in LDS, Q in regs, S[m][8] swizzle-transposed in LDS)
//         -> sparse bias corrections (<=28/row)
//         -> exact top-704 threshold (radix-256 select, 4 passes)
//         -> in-place softmax over kept -> PV (split-m across 4 waves, V from global).
// LDS: S 50.7KB + union(Kt 17KB | hist 16.1KB | red 8KB) + Qs 2KB => 2 blocks/CU.
// Grid is XCD-chunk swizzled: 176 row-blocks of one (b,h) stay on one XCD so
// that head's K+V (720KB; 4 heads/XCD = 2.9MB) is L2-resident.
// ---------------------------------------------------------------------------
__global__ __launch_bounds__(256, 2)
void attn_k(const float* __restrict__ Q, const float* __restrict__ K,
            const float* __restrict__ V, const float* __restrict__ rw,
            const int* __restrict__ sIdx, const float* __restrict__ sCoef,
            const int* __restrict__ sCnt, float* __restrict__ AO)
{
  __shared__ float S[SLEN];            // S[SIDX(m)+r], r=0..7
  __shared__ uint  U[4352];            // 17408B union: Kt(64*68 f32) | hist(32*129 u32) | red(2048 f32)
  __shared__ float Qs[512];
  __shared__ float rowZ[8];

  const int t   = threadIdx.x;
  // XCD-chunked bijective swizzle: 5632 = 8 * 704 exactly.
  const int bid = (int)((blockIdx.x & 7) * 704 + (blockIdx.x >> 3));
  const int bh = bid / RBLK;
  const int rb = bid % RBLK;
  const int l0 = rb * 8;
  const int b  = bh >> 3, h = bh & 7;

  const float* Qg = Q + (size_t)bh * LTOT * HD;
  const float* Kg = K + (size_t)bh * LTOT * HD;
  const float* Vg = V + (size_t)bh * LTOT * HD;

  if (t < 128) {
    const int row = t >> 4, d = (t & 15) << 2;
    *(float4*)&Qs[row * 64 + d] = *(const float4*)(Qg + (size_t)(l0 + row) * HD + d);
  }
  __syncthreads();

  // ---------------- scores ----------------
  {
    const int rp = t >> 6;        // wave id: rows rp and rp+4
    const int mm = t & 63;
    float4 qa[16], qb[16];        // 2 Q rows in registers (128 VGPR)
#pragma unroll
    for (int c = 0; c < 16; ++c) {
      qa[c] = *(const float4*)&Qs[rp * 64 + c * 4];
      qb[c] = *(const float4*)&Qs[(rp + 4) * 64 + c * 4];
    }
    float* Kt = (float*)U;        // [64][68]
    for (int kt = 0; kt < LTOT / 64; ++kt) {
      {
        const int row = t >> 2;
#pragma unroll
        for (int c4 = 0; c4 < 4; ++c4) {
          const int d = ((t & 3) + c4 * 4) << 2;
          *(float4*)&Kt[row * 68 + d] =
              *(const float4*)(Kg + (size_t)(kt * 64 + row) * HD + d);
        }
      }
      __syncthreads();
      const int m = kt * 64 + mm;
      float4 sa = make_float4(0,0,0,0), sb = make_float4(0,0,0,0);
#pragma unroll
      for (int c = 0; c < 16; ++c) {
        const float4 kv = *(const float4*)&Kt[mm * 68 + c * 4];
        sa.x = fmaf(qa[c].x, kv.x, sa.x); sa.y = fmaf(qa[c].y, kv.y, sa.y);
        sa.z = fmaf(qa[c].z, kv.z, sa.z); sa.w = fmaf(qa[c].w, kv.w, sa.w);
        sb.x = fmaf(qb[c].x, kv.x, sb.x); sb.y = fmaf(qb[c].y, kv.y, sb.y);
        sb.z = fmaf(qb[c].z, kv.z, sb.z); sb.w = fmaf(qb[c].w, kv.w, sb.w);
      }
      S[SIDX(m) + rp]     = (sa.x + sa.y) + (sa.z + sa.w);
      S[SIDX(m) + rp + 4] = (sb.x + sb.y) + (sb.z + sb.w);
      __syncthreads();
    }
  }

  // ---------------- sparse bias corrections (<=28 per row) ----------------
  {
    const int rr = t >> 5, jj = t & 31;
    const int l  = l0 + rr;
    if (jj < sCnt[l]) {
      const int   e = sIdx[l * SCAP + jj];
      const float c = sCoef[l * SCAP + jj];
      const int   m = e >> 2, ty = e & 3;
      const float w0 = rw[h * 3 + 0], w1 = rw[h * 3 + 1], w2 = rw[h * 3 + 2];
      const float d = (ty == 0) ? (w0 - w2) * c
                    : (ty == 1) ? (w1 - w2) * c
                                : -w2 * c;
      S[SIDX(m) + rr] += d;     // unique (m,rr) per entry -> no atomics needed
    }
  }
  // (radix pass 0 begins with __syncthreads)

  // ---------------- exact top-NKEEP threshold (radix select) ----------------
  const int r = t >> 5, j = t & 31;     // 32 threads per row
  uint* hist = U;                        // 32 sub-hists of 129 words (u16-pair packed)
  uint prefix = 0, rem = NKEEP;
  for (int p = 0; p < 4; ++p) {
    const int shift = 24 - 8 * p;
    const uint himask = (p == 0) ? 0u : (0xFFFFFFFFu << (8 * (4 - p)));
    __syncthreads();
    for (int i = t; i < 32 * 129; i += 256) hist[i] = 0;
    __syncthreads();
    uint* hr = hist + (r * 4 + (j & 3)) * 129;
    for (int i = j; i < LTOT; i += 32) {
      const uint u = fkey(S[SIDX(i) + r]);
      if ((u & himask) == prefix) {
        const uint bin = (u >> shift) & 255u;
        atomicAdd(&hr[bin >> 1], (bin & 1) ? 65536u : 1u);
      }
    }
    __syncthreads();
    // lane j covers bins [8j, 8j+7]
    uint c = 0;
#pragma unroll
    for (int bb = 0; bb < 8; ++bb) {
      const int bin = j * 8 + bb;
      const uint w = hist[(r*4+0)*129 + (bin>>1)] + hist[(r*4+1)*129 + (bin>>1)]
                   + hist[(r*4+2)*129 + (bin>>1)] + hist[(r*4+3)*129 + (bin>>1)];
      c += (bin & 1) ? (w >> 16) : (w & 0xFFFFu);
    }
    uint sfx = c;  // suffix sum over lanes >= j (descending-bin cumulative)
#pragma unroll
    for (int off = 1; off < 32; off <<= 1) {
      const uint o = __shfl_down(sfx, off, 32);
      if (j + off < 32) sfx += o;
    }
    const unsigned long long bal = __ballot(sfx >= rem);
    const uint halfb = (uint)(bal >> (t & 32));
    const int gs = 31 - __clz((int)halfb);         // highest lane with sfx >= rem
    uint above = __shfl(sfx, (gs + 1) & 31, 32);
    if (gs == 31) above = 0;
    uint rem2 = rem - above;
    int selbin = gs * 8;
#pragma unroll
    for (int bb = 7; bb >= 0; --bb) {
      const int bin = gs * 8 + bb;
      const uint w = hist[(r*4+0)*129 + (bin>>1)] + hist[(r*4+1)*129 + (bin>>1)]
                   + hist[(r*4+2)*129 + (bin>>1)] + hist[(r*4+3)*129 + (bin>>1)];
      const uint cnt = (bin & 1) ? (w >> 16) : (w & 0xFFFFu);
      if (rem2 <= cnt) { selbin = bin; break; }
      rem2 -= cnt;
    }
    prefix |= ((uint)selbin) << shift;
    rem = rem2;
  }
  const uint T = prefix;   // key of the NKEEP-th largest score in this row

  // ---------------- softmax over kept (in place: S <- unnormalized weights) ----
  float mx = -3.0e38f;
  for (int i = j; i < LTOT; i += 32) mx = fmaxf(mx, S[SIDX(i) + r]);
#pragma unroll
  for (int off = 16; off; off >>= 1) mx = fmaxf(mx, __shfl_xor(mx, off, 32));
  float z = 0.f;
  for (int i = j; i < LTOT; i += 32) {
    const float s = S[SIDX(i) + r];
    const float e = (fkey(s) >= T) ? __expf(s - mx) : 0.f;
    z += e;
    S[SIDX(i) + r] = e;
  }
#pragma unroll
  for (int off = 16; off; off >>= 1) z += __shfl_xor(z, off, 32);
  if (j == 0) rowZ[r] = z;
  __syncthreads();

  // ---------------- PV: split-m across waves, V direct from global -------------
  {
    const int g = t >> 6, lane = t & 63;
    float acc[8];
#pragma unroll
    for (int i = 0; i < 8; ++i) acc[i] = 0.f;
    const int mstart = g * (LTOT / 4), mend = mstart + LTOT / 4;
#pragma unroll 4
    for (int m = mstart; m < mend; ++m) {
      const float v = Vg[(size_t)m * HD + lane];
      const float4* wp = (const float4*)&S[SIDX(m)];   // uniform broadcast reads
      const float4 w0 = wp[0], w1 = wp[1];
      acc[0] = fmaf(w0.x, v, acc[0]); acc[1] = fmaf(w0.y, v, acc[1]);
      acc[2] = fmaf(w0.z, v, acc[2]); acc[3] = fmaf(w0.w, v, acc[3]);
      acc[4] = fmaf(w1.x, v, acc[4]); acc[5] = fmaf(w1.y, v, acc[5]);
      acc[6] = fmaf(w1.z, v, acc[6]); acc[7] = fmaf(w1.w, v, acc[7]);
    }
    float* red = (float*)U;   // [4][8][64]
#pragma unroll
    for (int i = 0; i < 8; ++i) red[(g * 8 + i) * 64 + lane] = acc[i];
  }
  __syncthreads();
  {
    float* red = (float*)U;
    for (int idx = t; idx < 512; idx += 256) {
      const int rr = idx >> 6, ln = idx & 63;
      const float o = (red[rr*64+ln] + red[512 + rr*64+ln] +
                       red[1024 + rr*64+ln] + red[1536 + rr*64+ln]) / rowZ[rr];
      AO[((size_t)b * LTOT + (l0 + rr)) * DIMD + h * HD + ln] = o;
    }
  }
}

// ---------------------------------------------------------------------------
extern "C" void kernel_launch(void* const* d_in, const int* in_sizes, int n_in,
                              void* d_out, int out_size, void* d_ws, size_t ws_size,
                              hipStream_t stream)
{
  (void)in_sizes; (void)n_in; (void)out_size; (void)ws_size;
  const float* x  = (const float*)d_in[0];
  const float* qw = (const float*)d_in[1];
  const float* pw = (const float*)d_in[2];
  const float* pb = (const float*)d_in[3];
  const float* rw = (const float*)d_in[4];
  const float* rm = (const float*)d_in[5];
  float* out = (float*)d_out;
  float* ws  = (float*)d_ws;

  const size_t NQ = (size_t)BATCH * HEADS * LTOT * HD;     // 2,883,584 floats
  float* Qb   = ws;
  float* Kb   = ws + NQ;
  float* Vb   = ws + 2 * NQ;
  float* AO   = ws + 3 * NQ;                                // [B, L, 512]
  float* sCo  = ws + 4 * NQ;                                // 1408*32 floats
  int*   sId  = (int*)(ws + 4 * NQ + LTOT * SCAP);          // 1408*32 ints
  int*   sCn  = (int*)(ws + 4 * NQ + 2 * LTOT * SCAP);      // 1408 ints
  // total ws: 4*2,883,584 + 2*45,056 + 1,408 floats = 46.5 MB

  sbias_k<<<dim3(352), dim3(256), 0, stream>>>(rm, sId, sCo, sCn);
  gemm_k<0><<<dim3(44 * 12), dim3(256), 0, stream>>>(x, qw, nullptr, Qb, Kb, Vb, 12);
  attn_k<<<dim3(32 * RBLK), dim3(256), 0, stream>>>(Qb, Kb, Vb, rw, sId, sCo, sCn, AO);
  gemm_k<1><<<dim3(44 * 4), dim3(256), 0, stream>>>(AO, pw, pb, out, nullptr, nullptr, 4);
}

// Round 5
// 830.793 us; speedup vs baseline: 1.2536x; 1.2536x over previous
//
#include <hip/hip_runtime.h>
#include <stdint.h>

// Problem constants (fixed by reference)
#define BATCH 4
#define LTOT  1408      // NVARS*NPATCH = 22*64
#define HEADS 8
#define HD    64
#define DIMD  512
#define NKEEP 704      // L - int(0.5*L)
#define RBLK  176      // LTOT/8
#define SCAP  32       // sparse-correction capacity per row (max actual = 28)

// S-buffer swizzle: logical (m, r) -> physical float index. XOR the float4-half
// position by (m>>2)&1: radix/softmax stride-8 scans spread 4 banks -> 8 banks
// (8-way -> 4-way conflict); scores-phase b128 writes become 2-way (free);
// PV broadcast reads stay wave-uniform (two float4s, halves swapped by m).
#define SADDR(m, r) (((m) << 3) + (((((r) >> 2) ^ (((m) >> 2) & 1))) << 2) + ((r) & 3))

typedef unsigned int uint;
typedef unsigned short ushort;
typedef __attribute__((ext_vector_type(8))) short bf16x8;
typedef __attribute__((ext_vector_type(4))) float f32x4;

__device__ __forceinline__ uint fkey(float f) {
  // order-preserving map float -> uint (ascending)
  uint u = __float_as_uint(f);
  return u ^ ((uint)((int)u >> 31) | 0x80000000u);
}

// Split f32 into bf16 hi + bf16 lo (x ~= hi + lo, rel err ~2^-17). RNE.
__device__ __forceinline__ void bf16split(float x, ushort& hi, ushort& lo) {
  uint u = __float_as_uint(x);
  uint h = (u + 0x7FFFu + ((u >> 16) & 1u)) & 0xFFFF0000u;
  hi = (ushort)(h >> 16);
  float r = x - __uint_as_float(h);
  uint v = __float_as_uint(r);
  lo = (ushort)((v + 0x7FFFu + ((v >> 16) & 1u)) >> 16);
}

// ---------------------------------------------------------------------------
// GEMM: C[M,N] = A[M,512] * W[N,512]^T.  128x128 tile, BK=16, 256 thr, 8x8 micro.
// MODE 0: qkv — Q,K written as bf16 hi/lo planes [B,H,L,64] (q pre-scaled);
//               V written f32.
// MODE 1: proj — plain store + bias add.
// ---------------------------------------------------------------------------
template<int MODE>
__global__ __launch_bounds__(256)
void gemm_k(const float* __restrict__ A, const float* __restrict__ W,
            const float* __restrict__ pb, ushort* __restrict__ QH,
            ushort* __restrict__ QL, ushort* __restrict__ KH,
            ushort* __restrict__ KL, float* __restrict__ C0, int ntiles)
{
  __shared__ float Ast[16][132];   // k-major, pad 132 (16B-aligned rows, bank-shifted)
  __shared__ float Bst[16][132];
  const int t  = threadIdx.x;
  const int mt = blockIdx.x / ntiles, nt = blockIdx.x % ntiles;
  const int m0 = mt * 128, n0 = nt * 128;
  const int lr = t >> 2;            // 0..63
  const int lk = (t & 3) << 2;      // 0,4,8,12
  const int tr = t >> 4, tc = t & 15;

  float acc[8][8];
#pragma unroll
  for (int i = 0; i < 8; ++i)
#pragma unroll
    for (int j = 0; j < 8; ++j) acc[i][j] = 0.f;

  for (int k0 = 0; k0 < DIMD; k0 += 16) {
#pragma unroll
    for (int hh = 0; hh < 2; ++hh) {
      const int row = lr + hh * 64;
      const float4 av = *(const float4*)(A + (size_t)(m0 + row) * DIMD + k0 + lk);
      Ast[lk + 0][row] = av.x; Ast[lk + 1][row] = av.y;
      Ast[lk + 2][row] = av.z; Ast[lk + 3][row] = av.w;
      const float4 wv = *(const float4*)(W + (size_t)(n0 + row) * DIMD + k0 + lk);
      Bst[lk + 0][row] = wv.x; Bst[lk + 1][row] = wv.y;
      Bst[lk + 2][row] = wv.z; Bst[lk + 3][row] = wv.w;
    }
    __syncthreads();
#pragma unroll
    for (int k = 0; k < 16; ++k) {
      const float4 a0 = *(const float4*)&Ast[k][tr * 8];
      const float4 a1 = *(const float4*)&Ast[k][tr * 8 + 4];
      const float4 b0 = *(const float4*)&Bst[k][tc * 8];
      const float4 b1 = *(const float4*)&Bst[k][tc * 8 + 4];
      const float a[8] = {a0.x,a0.y,a0.z,a0.w,a1.x,a1.y,a1.z,a1.w};
      const float b[8] = {b0.x,b0.y,b0.z,b0.w,b1.x,b1.y,b1.z,b1.w};
#pragma unroll
      for (int i = 0; i < 8; ++i)
#pragma unroll
        for (int j = 0; j < 8; ++j)
          acc[i][j] = fmaf(a[i], b[j], acc[i][j]);
    }
    __syncthreads();
  }

  const int nb = n0 + tc * 8;
  if (MODE == 0) {
    // n in [0,1536): which = n>>9, h = (n>>6)&7, d = n&63 (constant across the 8-chunk)
    const int which = nb >> 9;
    const int h  = (nb >> 6) & 7;
    const int d0 = nb & 63;
    const float scl = (which == 0) ? 0.125f : 1.0f;   // fold q * HD^-0.5
#pragma unroll
    for (int i = 0; i < 8; ++i) {
      const int gm = m0 + tr * 8 + i;
      const int bb = gm / LTOT, ll = gm % LTOT;
      const size_t off = ((size_t)(bb * HEADS + h) * LTOT + ll) * HD + d0;
      if (which == 2) {
        float4 v0 = make_float4(acc[i][0], acc[i][1], acc[i][2], acc[i][3]);
        float4 v1 = make_float4(acc[i][4], acc[i][5], acc[i][6], acc[i][7]);
        *(float4*)(C0 + off) = v0;
        *(float4*)(C0 + off + 4) = v1;
      } else {
        ushort* Hd = (which == 0) ? QH : KH;
        ushort* Ld = (which == 0) ? QL : KL;
        uint hw[4], lw[4];
#pragma unroll
        for (int jp = 0; jp < 4; ++jp) {
          ushort h0, l0v, h1, l1v;
          bf16split(acc[i][2*jp]     * scl, h0, l0v);
          bf16split(acc[i][2*jp + 1] * scl, h1, l1v);
          hw[jp] = (uint)h0 | ((uint)h1 << 16);
          lw[jp] = (uint)l0v | ((uint)l1v << 16);
        }
        *(uint4*)(Hd + off) = make_uint4(hw[0], hw[1], hw[2], hw[3]);
        *(uint4*)(Ld + off) = make_uint4(lw[0], lw[1], lw[2], lw[3]);
      }
    }
  } else {
    const float4 q0 = *(const float4*)(pb + nb);
    const float4 q1 = *(const float4*)(pb + nb + 4);
#pragma unroll
    for (int i = 0; i < 8; ++i) {
      const int gm = m0 + tr * 8 + i;
      float* p = C0 + (size_t)gm * DIMD + nb;
      float4 v0 = make_float4(acc[i][0]+q0.x, acc[i][1]+q0.y, acc[i][2]+q0.z, acc[i][3]+q0.w);
      float4 v1 = make_float4(acc[i][4]+q1.x, acc[i][5]+q1.y, acc[i][6]+q1.z, acc[i][7]+q1.w);
      *(float4*)p = v0;
      *(float4*)(p + 4) = v1;
    }
  }
}

// ---------------------------------------------------------------------------
// Sparse-bias builder. bias[h,l,m] = w2[h] (row-const, ordering/softmax
// invariant -> skipped) + (w0-w2)*S[l,m] + (w1-w2)*T[l,m] - w2*eye[l,m].
// <=28 sparse entries/row. One wave per row l, ballot compaction.
// ---------------------------------------------------------------------------
__global__ __launch_bounds__(256)
void sbias_k(const float* __restrict__ masks, int* __restrict__ sIdx,
             float* __restrict__ sCoef, int* __restrict__ sCnt)
{
  const int l    = blockIdx.x * 4 + (threadIdx.x >> 6);   // 352 blocks * 4 waves
  const int lane = threadIdx.x & 63;
  const unsigned long long ltmask = (1ull << lane) - 1ull;
  const float* Sm = masks + ((size_t)l * 3 + 0) * LTOT;
  const float* Tm = masks + ((size_t)l * 3 + 1) * LTOT;
  int base = 0;
  for (int i = lane; i < LTOT; i += 64) {
    const float sv = Sm[i];
    const float tv = Tm[i];
    const unsigned long long bS = __ballot(sv != 0.f);
    if (sv != 0.f) {
      const int pos = base + __popcll(bS & ltmask);
      if (pos < SCAP) { sIdx[l * SCAP + pos] = (i << 2) | 0; sCoef[l * SCAP + pos] = sv; }
    }
    base += __popcll(bS);
    const unsigned long long bT = __ballot(tv != 0.f);
    if (tv != 0.f) {
      const int pos = base + __popcll(bT & ltmask);
      if (pos < SCAP) { sIdx[l * SCAP + pos] = (i << 2) | 1; sCoef[l * SCAP + pos] = tv; }
    }
    base += __popcll(bT);
    const unsigned long long bD = __ballot(i == l);
    if (i == l) {
      const int pos = base + __popcll(bD & ltmask);
      if (pos < SCAP) { sIdx[l * SCAP + pos] = (i << 2) | 2; sCoef[l * SCAP + pos] = 1.f; }
    }
    base += __popcll(bD);
  }
  if (lane == 0) sCnt[l] = (base < SCAP) ? base : SCAP;
}

// ---------------------------------------------------------------------------
// Fused attention: per block = 8 query rows of one (b,h).
// Scores: bf16 MFMA 16x16x32, 3-term hi/lo (hi*hi + hi*lo + lo*hi ~= f32).
//   A-frags (Q) loaded once from global; B-frags (K) read per 16-m subtile
//   directly from L2 (XCD-chunked swizzle keeps head's K/V resident).
//   NO LDS staging, NO barriers in the scores loop. D rows 8..15 discarded.
// Then: sparse bias (<=28/row) -> exact top-704 radix select -> softmax ->
//   PV on VALU (split-m across 4 waves, V f32 from global, S broadcast reads).
// LDS: S 44KB + U 8.3KB (hist 16x129 | red 2048f | rowZ) = 53.4KB => 3 blk/CU.
// ---------------------------------------------------------------------------
__global__ __launch_bounds__(256, 3)
void attn_k(const ushort* __restrict__ QH, const ushort* __restrict__ QL,
            const ushort* __restrict__ KH, const ushort* __restrict__ KL,
            const float* __restrict__ V, const float* __restrict__ rw,
            const int* __restrict__ sIdx, const float* __restrict__ sCoef,
            const int* __restrict__ sCnt, float* __restrict__ AO)
{
  __shared__ float S[LTOT * 8];        // 45056B, swizzled: S[SADDR(m, r)]
  __shared__ uint  U[2080];            // 8320B: hist 16*129 | red 2048 f32; rowZ @2072

  const int t   = threadIdx.x;
  // XCD-chunked bijective swizzle: 5632 = 8 * 704 exactly.
  const int bid = (int)((blockIdx.x & 7) * 704 + (blockIdx.x >> 3));
  const int bh = bid / RBLK;
  const int rb = bid % RBLK;
  const int l0 = rb * 8;
  const int b  = bh >> 3, h = bh & 7;

  const float* Vg = V + (size_t)bh * LTOT * HD;
  const int lane = t & 63;
  const int g    = t >> 6;             // wave id

  // ---------------- scores (MFMA, no barriers) ----------------
  {
    // A-frags: row = lane&15 (query rows l0..l0+15; rows 8-15 unused junk),
    // k = 8*(lane>>4)+j, d = c*32 + k.
    int ar = l0 + (lane & 15);
    if (ar >= LTOT) ar = LTOT - 1;
    const size_t qb = ((size_t)bh * LTOT + ar) * HD + 8 * (lane >> 4);
    const bf16x8 aH0 = *(const bf16x8*)(QH + qb);
    const bf16x8 aH1 = *(const bf16x8*)(QH + qb + 32);
    const bf16x8 aL0 = *(const bf16x8*)(QL + qb);
    const bf16x8 aL1 = *(const bf16x8*)(QL + qb + 32);

#pragma unroll 2
    for (int it = 0; it < 22; ++it) {
      const int m = g * 352 + it * 16 + (lane & 15);   // B col = lane&15
      const size_t kb = ((size_t)bh * LTOT + m) * HD + 8 * (lane >> 4);
      const bf16x8 bH0 = *(const bf16x8*)(KH + kb);
      const bf16x8 bH1 = *(const bf16x8*)(KH + kb + 32);
      const bf16x8 bL0 = *(const bf16x8*)(KL + kb);
      const bf16x8 bL1 = *(const bf16x8*)(KL + kb + 32);
      f32x4 acc = {0.f, 0.f, 0.f, 0.f};
      acc = __builtin_amdgcn_mfma_f32_16x16x32_bf16(aH0, bH0, acc, 0, 0, 0);
      acc = __builtin_amdgcn_mfma_f32_16x16x32_bf16(aH1, bH1, acc, 0, 0, 0);
      acc = __builtin_amdgcn_mfma_f32_16x16x32_bf16(aH0, bL0, acc, 0, 0, 0);
      acc = __builtin_amdgcn_mfma_f32_16x16x32_bf16(aH1, bL1, acc, 0, 0, 0);
      acc = __builtin_amdgcn_mfma_f32_16x16x32_bf16(aL0, bH0, acc, 0, 0, 0);
      acc = __builtin_amdgcn_mfma_f32_16x16x32_bf16(aL1, bH1, acc, 0, 0, 0);
      // D: col=lane&15 (=m), row=4*(lane>>4)+reg; rows 0-7 live in lanes 0-31.
      // Swizzled write: float4 half-position = (lane>>4) ^ ((m>>2)&1).
      if (lane < 32) {
        *(float4*)&S[m * 8 + 4 * ((lane >> 4) ^ ((m >> 2) & 1))] =
            make_float4(acc[0], acc[1], acc[2], acc[3]);
      }
    }
  }
  __syncthreads();

  // ---------------- sparse bias corrections (<=28 per row) ----------------
  {
    const int rr = t >> 5, jj = t & 31;
    const int l  = l0 + rr;
    if (jj < sCnt[l]) {
      const int   e = sIdx[l * SCAP + jj];
      const float c = sCoef[l * SCAP + jj];
      const int   m = e >> 2, ty = e & 3;
      const float w0 = rw[h * 3 + 0], w1 = rw[h * 3 + 1], w2 = rw[h * 3 + 2];
      const float d = (ty == 0) ? (w0 - w2) * c
                    : (ty == 1) ? (w1 - w2) * c
                                : -w2 * c;
      S[SADDR(m, rr)] += d;     // unique (m,rr) per entry -> no atomics needed
    }
  }
  // (radix pass 0 begins with __syncthreads)

  // ---------------- exact top-NKEEP threshold (radix select) ----------------
  const int r = t >> 5, j = t & 31;     // 32 threads per row
  uint* hist = U;                        // 16 sub-hists (2/row) of 129 u16-pair words
  uint prefix = 0, rem = NKEEP;
  for (int p = 0; p < 4; ++p) {
    const int shift = 24 - 8 * p;
    const uint himask = (p == 0) ? 0u : (0xFFFFFFFFu << (8 * (4 - p)));
    __syncthreads();
    for (int i = t; i < 16 * 129; i += 256) hist[i] = 0;
    __syncthreads();
    uint* hr = hist + (r * 2 + (j & 1)) * 129;
    for (int i = j; i < LTOT; i += 32) {
      const uint u = fkey(S[SADDR(i, r)]);
      if ((u & himask) == prefix) {
        const uint bin = (u >> shift) & 255u;
        atomicAdd(&hr[bin >> 1], (bin & 1) ? 65536u : 1u);
      }
    }
    __syncthreads();
    // lane j covers bins [8j, 8j+7]
    uint c = 0;
#pragma unroll
    for (int bb = 0; bb < 8; ++bb) {
      const int bin = j * 8 + bb;
      const uint w = hist[(r*2+0)*129 + (bin>>1)] + hist[(r*2+1)*129 + (bin>>1)];
      c += (bin & 1) ? (w >> 16) : (w & 0xFFFFu);
    }
    uint sfx = c;  // suffix sum over lanes >= j (descending-bin cumulative)
#pragma unroll
    for (int off = 1; off < 32; off <<= 1) {
      const uint o = __shfl_down(sfx, off, 32);
      if (j + off < 32) sfx += o;
    }
    const unsigned long long bal = __ballot(sfx >= rem);
    const uint halfb = (uint)(bal >> (t & 32));
    const int gs = 31 - __clz((int)halfb);         // highest lane with sfx >= rem
    uint above = __shfl(sfx, (gs + 1) & 31, 32);
    if (gs == 31) above = 0;
    uint rem2 = rem - above;
    int selbin = gs * 8;
#pragma unroll
    for (int bb = 7; bb >= 0; --bb) {
      const int bin = gs * 8 + bb;
      const uint w = hist[(r*2+0)*129 + (bin>>1)] + hist[(r*2+1)*129 + (bin>>1)];
      const uint cnt = (bin & 1) ? (w >> 16) : (w & 0xFFFFu);
      if (rem2 <= cnt) { selbin = bin; break; }
      rem2 -= cnt;
    }
    prefix |= ((uint)selbin) << shift;
    rem = rem2;
  }
  const uint T = prefix;   // key of the NKEEP-th largest score in this row

  // ---------------- softmax over kept (in place: S <- unnormalized weights) ----
  float mx = -3.0e38f;
  for (int i = j; i < LTOT; i += 32) mx = fmaxf(mx, S[SADDR(i, r)]);
#pragma unroll
  for (int off = 16; off; off >>= 1) mx = fmaxf(mx, __shfl_xor(mx, off, 32));
  float z = 0.f;
  for (int i = j; i < LTOT; i += 32) {
    const float s = S[SADDR(i, r)];
    const float e = (fkey(s) >= T) ? __expf(s - mx) : 0.f;
    z += e;
    S[SADDR(i, r)] = e;
  }
#pragma unroll
  for (int off = 16; off; off >>= 1) z += __shfl_xor(z, off, 32);
  float* rowZ = (float*)&U[2072];
  if (j == 0) rowZ[r] = z;
  __syncthreads();

  // ---------------- PV: split-m across waves, V direct from global -------------
  {
    float acc[8];
#pragma unroll
    for (int i = 0; i < 8; ++i) acc[i] = 0.f;
    const int mstart = g * (LTOT / 4), mend = mstart + LTOT / 4;
#pragma unroll 4
    for (int m = mstart; m < mend; ++m) {
      const float v = Vg[(size_t)m * HD + lane];
      const int x = ((m >> 2) & 1) << 2;           // swizzled half positions
      const float4 w0 = *(const float4*)&S[m * 8 + x];        // rows 0-3
      const float4 w1 = *(const float4*)&S[m * 8 + (4 ^ x)];  // rows 4-7
      acc[0] = fmaf(w0.x, v, acc[0]); acc[1] = fmaf(w0.y, v, acc[1]);
      acc[2] = fmaf(w0.z, v, acc[2]); acc[3] = fmaf(w0.w, v, acc[3]);
      acc[4] = fmaf(w1.x, v, acc[4]); acc[5] = fmaf(w1.y, v, acc[5]);
      acc[6] = fmaf(w1.z, v, acc[6]); acc[7] = fmaf(w1.w, v, acc[7]);
    }
    float* red = (float*)U;   // [4][8][64]
#pragma unroll
    for (int i = 0; i < 8; ++i) red[(g * 8 + i) * 64 + lane] = acc[i];
  }
  __syncthreads();
  {
    float* red = (float*)U;
    float* rowZp = (float*)&U[2072];
    for (int idx = t; idx < 512; idx += 256) {
      const int rr = idx >> 6, ln = idx & 63;
      const float o = (red[rr*64+ln] + red[512 + rr*64+ln] +
                       red[1024 + rr*64+ln] + red[1536 + rr*64+ln]) / rowZp[rr];
      AO[((size_t)b * LTOT + (l0 + rr)) * DIMD + h * HD + ln] = o;
    }
  }
}

// ---------------------------------------------------------------------------
extern "C" void kernel_launch(void* const* d_in, const int* in_sizes, int n_in,
                              void* d_out, int out_size, void* d_ws, size_t ws_size,
                              hipStream_t stream)
{
  (void)in_sizes; (void)n_in; (void)out_size; (void)ws_size;
  const float* x  = (const float*)d_in[0];
  const float* qw = (const float*)d_in[1];
  const float* pw = (const float*)d_in[2];
  const float* pb = (const float*)d_in[3];
  const float* rw = (const float*)d_in[4];
  const float* rm = (const float*)d_in[5];
  float* out = (float*)d_out;
  float* ws  = (float*)d_ws;

  const size_t NQ = (size_t)BATCH * HEADS * LTOT * HD;     // 2,883,584 elems
  ushort* QH = (ushort*)ws;            // NQ u16 = NQ/2 floats
  ushort* QL = QH + NQ;
  ushort* KH = QH + 2 * NQ;
  ushort* KL = QH + 3 * NQ;
  float*  Vb = ws + 2 * NQ;
  float*  AO = ws + 3 * NQ;                                 // [B, L, 512]
  float*  sCo = ws + 4 * NQ;                                // 1408*32 floats
  int*    sId = (int*)(ws + 4 * NQ + LTOT * SCAP);          // 1408*32 ints
  int*    sCn = (int*)(ws + 4 * NQ + 2 * LTOT * SCAP);      // 1408 ints
  // total ws: 4*NQ + 2*45,056 + 1,408 floats = 46.5 MB

  sbias_k<<<dim3(352), dim3(256), 0, stream>>>(rm, sId, sCo, sCn);
  gemm_k<0><<<dim3(44 * 12), dim3(256), 0, stream>>>(x, qw, nullptr, QH, QL, KH, KL, Vb, 12);
  attn_k<<<dim3(32 * RBLK), dim3(256), 0, stream>>>(QH, QL, KH, KL, Vb, rw, sId, sCo, sCn, AO);
  gemm_k<1><<<dim3(44 * 4), dim3(256), 0, stream>>>(AO, pw, pb, nullptr, nullptr, nullptr, nullptr, out, 4);
}